// Round 3
// baseline (1537.110 us; speedup 1.0000x reference)
//
#include <hip/hip_runtime.h>

// GCN3 fused: per layer, one kernel. Blocks own 512-node ranges, accumulate
// segment-sum in LDS (no global atomics, no CSR/sort), then apply the dense
// layer + bias + LeakyReLU from LDS and write the result.
// Edge membership test uses a precomputed byte array bid[e] = dst[e]>>9 and
// SWAR zero-byte matching on uint4 loads (16 edges per load).

#define THREADS 1024
#define RANGE   512          // nodes per block (2^9)
#define QCAP    16384        // queue capacity (expected ~8.2K matches/block)

__global__ void bid_kernel(const int* __restrict__ dst,
                           unsigned char* __restrict__ bid, int nE) {
    int i = blockIdx.x * blockDim.x + threadIdx.x;
    if (i < nE) bid[i] = (unsigned char)(dst[i] >> 9);
}

template <int FOUT, bool RELU>
__global__ __launch_bounds__(THREADS, 1)
void layer_kernel(const float* __restrict__ t,      // [n][32] input features
                  const int* __restrict__ src,
                  const int* __restrict__ dst,
                  const unsigned char* __restrict__ bid,
                  const float* __restrict__ W,      // [32][FOUT]
                  const float* __restrict__ b,      // [FOUT]
                  float* __restrict__ out,          // [n][FOUT]
                  int n, int nE) {
    constexpr int FIN = 32;
    __shared__ float    acc[RANGE * 33];    // +1 pad word per row: conflict-free
    __shared__ unsigned q[QCAP];            // packed (dloc<<17)|src
    __shared__ float    sW[FIN * FOUT];
    __shared__ float    sb[FOUT];
    __shared__ unsigned qcnt;

    const int tid   = threadIdx.x;
    const int rid   = blockIdx.x;
    const int nbase = rid << 9;

    for (int i = tid; i < RANGE * 33; i += THREADS) acc[i] = 0.0f;
    for (int i = tid; i < FIN * FOUT; i += THREADS) sW[i] = W[i];
    if (tid < FOUT) sb[tid] = b[tid];
    if (tid == 0) qcnt = 0u;
    __syncthreads();

    // ---- Phase 1: scan all edge bucket-ids, queue matches ----
    const unsigned pat = 0x01010101u * (unsigned)rid;
    const uint4* bidv = (const uint4*)bid;
    const int nv = nE >> 4;                 // uint4 chunks (16 edges each)
#pragma unroll 2
    for (int idx = tid; idx < nv; idx += THREADS) {
        uint4 v = bidv[idx];
        unsigned x0 = v.x ^ pat, x1 = v.y ^ pat, x2 = v.z ^ pat, x3 = v.w ^ pat;
        // exact per-byte zero detect -> 0x80 flag per matching byte
        unsigned z0 = ~(x0 | ((x0 & 0x7f7f7f7fu) + 0x7f7f7f7fu)) & 0x80808080u;
        unsigned z1 = ~(x1 | ((x1 & 0x7f7f7f7fu) + 0x7f7f7f7fu)) & 0x80808080u;
        unsigned z2 = ~(x2 | ((x2 & 0x7f7f7f7fu) + 0x7f7f7f7fu)) & 0x80808080u;
        unsigned z3 = ~(x3 | ((x3 & 0x7f7f7f7fu) + 0x7f7f7f7fu)) & 0x80808080u;
        if (z0 | z1 | z2 | z3) {
            int e0 = idx << 4;
            unsigned zs[4] = {z0, z1, z2, z3};
#pragma unroll
            for (int w = 0; w < 4; ++w) {
                unsigned z = zs[w];
                while (z) {
                    int byte = (__ffs(z) - 1) >> 3;   // bits 7/15/23/31 only
                    z &= z - 1;
                    int e = e0 + w * 4 + byte;
                    unsigned pos = atomicAdd(&qcnt, 1u);
                    int s  = src[e];
                    int dl = dst[e] - nbase;          // 0..511
                    if (pos < QCAP) q[pos] = ((unsigned)dl << 17) | (unsigned)s;
                }
            }
        }
    }
    // tail edges (nE not multiple of 16)
    int tail = nE & 15;
    if (tid < tail) {
        int e = (nv << 4) + tid;
        if (bid[e] == (unsigned char)rid) {
            unsigned pos = atomicAdd(&qcnt, 1u);
            int s  = src[e];
            int dl = dst[e] - nbase;
            if (pos < QCAP) q[pos] = ((unsigned)dl << 17) | (unsigned)s;
        }
    }
    __syncthreads();

    // ---- Phase 2: drain queue. 32-lane group per entry; coalesced 128B row
    // gather + bank-conflict-free LDS f32 atomic add. 4-way unroll for MLP. ----
    const int lane31 = tid & 31;
    const int grp    = tid >> 5;            // 0..31 groups
    int qn = (int)qcnt; if (qn > QCAP) qn = QCAP;
    int i = grp;
    for (; i + 96 < qn; i += 128) {
        unsigned p0 = q[i], p1 = q[i + 32], p2 = q[i + 64], p3 = q[i + 96];
        float v0 = t[(size_t)(p0 & 0x1ffffu) * FIN + lane31];
        float v1 = t[(size_t)(p1 & 0x1ffffu) * FIN + lane31];
        float v2 = t[(size_t)(p2 & 0x1ffffu) * FIN + lane31];
        float v3 = t[(size_t)(p3 & 0x1ffffu) * FIN + lane31];
        atomicAdd(&acc[(p0 >> 17) * 33 + lane31], v0);
        atomicAdd(&acc[(p1 >> 17) * 33 + lane31], v1);
        atomicAdd(&acc[(p2 >> 17) * 33 + lane31], v2);
        atomicAdd(&acc[(p3 >> 17) * 33 + lane31], v3);
    }
    for (; i < qn; i += 32) {
        unsigned p = q[i];
        float v = t[(size_t)(p & 0x1ffffu) * FIN + lane31];
        atomicAdd(&acc[(p >> 17) * 33 + lane31], v);
    }
    __syncthreads();

    // ---- Phase 3: dense (32 -> FOUT) + bias + optional LeakyReLU ----
    // thread pair per node: each thread computes FOUT/2 outputs
    constexpr int FH = FOUT / 2;
    const int lrow = tid >> 1;              // 0..511
    const int node = nbase + lrow;
    const int half = tid & 1;
    if (node < n) {
        float r[FH];
#pragma unroll
        for (int j = 0; j < FH; ++j) r[j] = sb[half * FH + j];
#pragma unroll
        for (int k = 0; k < FIN; ++k) {
            float a = acc[lrow * 33 + k];   // (lrow+k)%32 banks: conflict-free
#pragma unroll
            for (int j = 0; j < FH; ++j) r[j] += a * sW[k * FOUT + half * FH + j];
        }
        if (RELU) {
#pragma unroll
            for (int j = 0; j < FH; ++j) r[j] = r[j] >= 0.0f ? r[j] : 0.1f * r[j];
        }
        float4* op = (float4*)(out + (size_t)node * FOUT + half * FH);
#pragma unroll
        for (int j4 = 0; j4 < FH / 4; ++j4) {
            float4 v;
            v.x = r[j4 * 4 + 0]; v.y = r[j4 * 4 + 1];
            v.z = r[j4 * 4 + 2]; v.w = r[j4 * 4 + 3];
            op[j4] = v;
        }
    }
}

extern "C" void kernel_launch(void* const* d_in, const int* in_sizes, int n_in,
                              void* d_out, int out_size, void* d_ws, size_t ws_size,
                              hipStream_t stream) {
    const float* x  = (const float*)d_in[0];
    const int* src  = (const int*)d_in[1];
    const int* dst  = (const int*)d_in[2];
    const float* W1 = (const float*)d_in[3];
    const float* b1 = (const float*)d_in[4];
    const float* W2 = (const float*)d_in[5];
    const float* b2 = (const float*)d_in[6];
    const float* W3 = (const float*)d_in[7];
    const float* b3 = (const float*)d_in[8];
    float* out = (float*)d_out;

    const int n  = in_sizes[0] / 32;     // 100000
    const int nE = in_sizes[1];          // 1600000

    float* h1 = (float*)d_ws;                       // n*32 floats
    float* h2 = h1 + (size_t)n * 32;                // n*32 floats
    unsigned char* bid = (unsigned char*)(h2 + (size_t)n * 32);  // nE bytes

    const int nranges = (n + RANGE - 1) / RANGE;    // 196

    bid_kernel<<<(nE + 255) / 256, 256, 0, stream>>>(dst, bid, nE);
    layer_kernel<32, true ><<<nranges, THREADS, 0, stream>>>(x,  src, dst, bid, W1, b1, h1, n, nE);
    layer_kernel<32, true ><<<nranges, THREADS, 0, stream>>>(h1, src, dst, bid, W2, b2, h2, n, nE);
    layer_kernel<16, false><<<nranges, THREADS, 0, stream>>>(h2, src, dst, bid, W3, b3, out, n, nE);
}

// Round 4
// 914.250 us; speedup vs baseline: 1.6813x; 1.6813x over previous
//
#include <hip/hip_runtime.h>

// GCN3: partition edges once into 128-node dst-buckets (packed u32 entries),
// then per layer: one block per bucket aggregates in LDS (no global atomics)
// and applies the dense layer + bias + LeakyReLU in-place.
// Layer 3 transforms first (32->16) so the final aggregate is 16-wide.

#define RANGE_BITS 7
#define RANGE      128                  // nodes per bucket
#define MAXBK      1024                 // max buckets supported by LDS tables
#define CHUNK      8192                 // edges per fill block
#define FILL_T     512
#define LAYER_T    512

// ---------------- partition build ----------------

__global__ void hist_kernel(const int* __restrict__ dst, int* __restrict__ ghist,
                            int nE, int nbk) {
    __shared__ int h[MAXBK];
    const int tid = threadIdx.x;
    for (int i = tid; i < nbk; i += blockDim.x) h[i] = 0;
    __syncthreads();
    const int stride = gridDim.x * blockDim.x;
    for (int e = blockIdx.x * blockDim.x + tid; e < nE; e += stride)
        atomicAdd(&h[dst[e] >> RANGE_BITS], 1);
    __syncthreads();
    for (int i = tid; i < nbk; i += blockDim.x) {
        int c = h[i];
        if (c) atomicAdd(&ghist[i], c);
    }
}

// single block: exclusive scan of ghist[0..nbk) -> off[0..nbk], gcur = off
__global__ void scan_kernel(int* __restrict__ ghist, int* __restrict__ off,
                            int* __restrict__ gcur, int nbk) {
    __shared__ int lds[MAXBK];
    const int tid = threadIdx.x;
    for (int i = tid; i < nbk; i += blockDim.x) lds[i] = ghist[i];
    __syncthreads();
    // Hillis-Steele inclusive (nbk <= blockDim.x assumed; nbk=782, T=1024)
    for (int o = 1; o < nbk; o <<= 1) {
        int v = (tid >= o && tid < nbk) ? lds[tid - o] : 0;
        __syncthreads();
        if (tid < nbk) lds[tid] += v;
        __syncthreads();
    }
    if (tid < nbk) {
        int ex = (tid == 0) ? 0 : lds[tid - 1];
        off[tid]  = ex;
        gcur[tid] = ex;
        if (tid == nbk - 1) off[nbk] = lds[tid];
    }
}

// two-pass chunked fill: count chunk's per-bucket entries, reserve global
// ranges, then write packed entries into contiguous runs.
__global__ __launch_bounds__(FILL_T)
void fill_kernel(const int* __restrict__ src, const int* __restrict__ dst,
                 int* __restrict__ gcur, unsigned* __restrict__ edata,
                 int nE, int nbk) {
    __shared__ int cnt[MAXBK];
    __shared__ int base[MAXBK];
    const int tid = threadIdx.x;
    const int c0 = blockIdx.x * CHUNK;
    const int c1 = min(c0 + CHUNK, nE);
    for (int i = tid; i < nbk; i += FILL_T) cnt[i] = 0;
    __syncthreads();
    for (int e = c0 + tid; e < c1; e += FILL_T)
        atomicAdd(&cnt[dst[e] >> RANGE_BITS], 1);
    __syncthreads();
    for (int i = tid; i < nbk; i += FILL_T) {
        int c = cnt[i];
        base[i] = c ? atomicAdd(&gcur[i], c) : 0;
        cnt[i] = 0;
    }
    __syncthreads();
    for (int e = c0 + tid; e < c1; e += FILL_T) {
        int d = dst[e];
        int bk = d >> RANGE_BITS;
        int pos = base[bk] + atomicAdd(&cnt[bk], 1);
        edata[pos] = ((unsigned)(d & (RANGE - 1)) << 17) | (unsigned)src[e];
    }
}

// ---------------- fused aggregate + dense ----------------

template <int FOUT, bool RELU>
__global__ __launch_bounds__(LAYER_T, 4)
void layer_kernel(const float* __restrict__ t,        // [n][32]
                  const unsigned* __restrict__ edata,
                  const int* __restrict__ off,
                  const float* __restrict__ W,        // [32][FOUT]
                  const float* __restrict__ b,
                  float* __restrict__ out,            // [n][FOUT]
                  int n) {
    constexpr int FIN = 32;
    __shared__ float acc[RANGE * 33];                 // pad: conflict-free
    __shared__ float sW[FIN * FOUT];
    __shared__ float sb[FOUT];

    const int tid   = threadIdx.x;
    const int rid   = blockIdx.x;
    const int nbase = rid << RANGE_BITS;

    for (int i = tid; i < RANGE * 33; i += LAYER_T) acc[i] = 0.0f;
    for (int i = tid; i < FIN * FOUT; i += LAYER_T) sW[i] = W[i];
    if (tid < FOUT) sb[tid] = b[tid];
    __syncthreads();

    const int e0  = off[rid];
    const int cnt = off[rid + 1] - e0;
    const int grp    = tid >> 5;                      // 16 groups
    const int lane31 = tid & 31;
    const unsigned* eb = edata + e0;

    int i = grp;
    for (; i + 48 < cnt; i += 64) {
        unsigned p0 = eb[i], p1 = eb[i + 16], p2 = eb[i + 32], p3 = eb[i + 48];
        float v0 = t[(size_t)(p0 & 0x1ffffu) * FIN + lane31];
        float v1 = t[(size_t)(p1 & 0x1ffffu) * FIN + lane31];
        float v2 = t[(size_t)(p2 & 0x1ffffu) * FIN + lane31];
        float v3 = t[(size_t)(p3 & 0x1ffffu) * FIN + lane31];
        atomicAdd(&acc[(p0 >> 17) * 33 + lane31], v0);
        atomicAdd(&acc[(p1 >> 17) * 33 + lane31], v1);
        atomicAdd(&acc[(p2 >> 17) * 33 + lane31], v2);
        atomicAdd(&acc[(p3 >> 17) * 33 + lane31], v3);
    }
    for (; i < cnt; i += 16) {
        unsigned p = eb[i];
        float v = t[(size_t)(p & 0x1ffffu) * FIN + lane31];
        atomicAdd(&acc[(p >> 17) * 33 + lane31], v);
    }
    __syncthreads();

    // dense: thread -> (node quarter): lrow = tid>>2 in [0,128), q = tid&3
    constexpr int QO = FOUT / 4;
    const int lrow = tid >> 2;
    const int q    = tid & 3;
    const int node = nbase + lrow;
    if (node < n) {
        float r[QO];
#pragma unroll
        for (int j = 0; j < QO; ++j) r[j] = sb[q * QO + j];
#pragma unroll
        for (int k = 0; k < FIN; ++k) {
            float a = acc[lrow * 33 + k];
#pragma unroll
            for (int j = 0; j < QO; ++j) r[j] += a * sW[k * FOUT + q * QO + j];
        }
        if (RELU) {
#pragma unroll
            for (int j = 0; j < QO; ++j) r[j] = r[j] >= 0.0f ? r[j] : 0.1f * r[j];
        }
        float4* op = (float4*)(out + (size_t)node * FOUT + q * QO);
#pragma unroll
        for (int j4 = 0; j4 < QO / 4; ++j4) {
            float4 v;
            v.x = r[j4 * 4 + 0]; v.y = r[j4 * 4 + 1];
            v.z = r[j4 * 4 + 2]; v.w = r[j4 * 4 + 3];
            op[j4] = v;
        }
    }
}

// 16-wide aggregate of pre-transformed features, bias-initialized (layer 3)
__global__ __launch_bounds__(LAYER_T, 4)
void agg16_kernel(const float* __restrict__ t3,      // [n][16]
                  const unsigned* __restrict__ edata,
                  const int* __restrict__ off,
                  const float* __restrict__ b,       // [16]
                  float* __restrict__ out,           // [n][16]
                  int n) {
    __shared__ float acc[RANGE * 17];
    __shared__ float sb[16];
    const int tid   = threadIdx.x;
    const int rid   = blockIdx.x;
    const int nbase = rid << RANGE_BITS;

    if (tid < 16) sb[tid] = b[tid];
    __syncthreads();
    for (int i = tid; i < RANGE * 17; i += LAYER_T) {
        int l = i % 17;
        acc[i] = (l < 16) ? sb[l] : 0.0f;             // bias init
    }
    __syncthreads();

    const int e0  = off[rid];
    const int cnt = off[rid + 1] - e0;
    const int grp    = tid >> 4;                      // 32 groups of 16
    const int lane15 = tid & 15;
    const unsigned* eb = edata + e0;

    int i = grp;
    for (; i + 96 < cnt; i += 128) {
        unsigned p0 = eb[i], p1 = eb[i + 32], p2 = eb[i + 64], p3 = eb[i + 96];
        float v0 = t3[(size_t)(p0 & 0x1ffffu) * 16 + lane15];
        float v1 = t3[(size_t)(p1 & 0x1ffffu) * 16 + lane15];
        float v2 = t3[(size_t)(p2 & 0x1ffffu) * 16 + lane15];
        float v3 = t3[(size_t)(p3 & 0x1ffffu) * 16 + lane15];
        atomicAdd(&acc[(p0 >> 17) * 17 + lane15], v0);
        atomicAdd(&acc[(p1 >> 17) * 17 + lane15], v1);
        atomicAdd(&acc[(p2 >> 17) * 17 + lane15], v2);
        atomicAdd(&acc[(p3 >> 17) * 17 + lane15], v3);
    }
    for (; i < cnt; i += 32) {
        unsigned p = eb[i];
        float v = t3[(size_t)(p & 0x1ffffu) * 16 + lane15];
        atomicAdd(&acc[(p >> 17) * 17 + lane15], v);
    }
    __syncthreads();

    for (int idx = tid; idx < RANGE * 16; idx += LAYER_T) {
        int lrow = idx >> 4, l = idx & 15;
        int node = nbase + lrow;
        if (node < n) out[(size_t)node * 16 + l] = acc[lrow * 17 + l];
    }
}

// plain dense (pre-transform for layer 3)
template <int IN, int OUT>
__global__ void dense_kernel(const float* __restrict__ in,
                             const float* __restrict__ W,
                             float* __restrict__ out, int n) {
    __shared__ float sW[IN * OUT];
    for (int i = threadIdx.x; i < IN * OUT; i += blockDim.x) sW[i] = W[i];
    __syncthreads();
    int node = blockIdx.x * blockDim.x + threadIdx.x;
    if (node >= n) return;
    float row[IN];
    const float4* rp = (const float4*)(in + (size_t)node * IN);
#pragma unroll
    for (int k4 = 0; k4 < IN / 4; ++k4) {
        float4 v = rp[k4];
        row[k4 * 4] = v.x; row[k4 * 4 + 1] = v.y;
        row[k4 * 4 + 2] = v.z; row[k4 * 4 + 3] = v.w;
    }
    float acc[OUT];
#pragma unroll
    for (int j = 0; j < OUT; ++j) acc[j] = 0.0f;
#pragma unroll
    for (int k = 0; k < IN; ++k) {
        float a = row[k];
#pragma unroll
        for (int j = 0; j < OUT; ++j) acc[j] += a * sW[k * OUT + j];
    }
    float4* op = (float4*)(out + (size_t)node * OUT);
#pragma unroll
    for (int j4 = 0; j4 < OUT / 4; ++j4) {
        float4 v;
        v.x = acc[j4 * 4]; v.y = acc[j4 * 4 + 1];
        v.z = acc[j4 * 4 + 2]; v.w = acc[j4 * 4 + 3];
        op[j4] = v;
    }
}

// ---------------- fallback: round-1 atomic scatter ----------------

template <int F>
__global__ void scatter_kernel(const float* __restrict__ h, const int* __restrict__ src,
                               const int* __restrict__ dst, float* __restrict__ agg,
                               int n_edges) {
    int gid = blockIdx.x * blockDim.x + threadIdx.x;
    int e = gid / F, f = gid & (F - 1);
    if (e >= n_edges) return;
    unsafeAtomicAdd(&agg[(size_t)dst[e] * F + f], h[(size_t)src[e] * F + f]);
}

template <int IN, int OUT, bool RELU>
__global__ void dense_bias_kernel(const float* __restrict__ in, const float* __restrict__ W,
                                  const float* __restrict__ b, float* __restrict__ out, int n) {
    __shared__ float sW[IN * OUT];
    __shared__ float sb[OUT];
    for (int i = threadIdx.x; i < IN * OUT; i += blockDim.x) sW[i] = W[i];
    for (int i = threadIdx.x; i < OUT; i += blockDim.x) sb[i] = b[i];
    __syncthreads();
    int node = blockIdx.x * blockDim.x + threadIdx.x;
    if (node >= n) return;
    float acc[OUT];
#pragma unroll
    for (int j = 0; j < OUT; ++j) acc[j] = sb[j];
#pragma unroll
    for (int k = 0; k < IN; ++k) {
        float a = in[(size_t)node * IN + k];
#pragma unroll
        for (int j = 0; j < OUT; ++j) acc[j] += a * sW[k * OUT + j];
    }
#pragma unroll
    for (int j = 0; j < OUT; ++j) {
        float v = acc[j];
        out[(size_t)node * OUT + j] = (RELU && v < 0.0f) ? 0.1f * v : v;
    }
}

__global__ void init_out_kernel(float* __restrict__ out, const float* __restrict__ b,
                                int total) {
    int gid = blockIdx.x * blockDim.x + threadIdx.x;
    if (gid < total) out[gid] = b[gid & 15];
}

// ---------------- launch ----------------

extern "C" void kernel_launch(void* const* d_in, const int* in_sizes, int n_in,
                              void* d_out, int out_size, void* d_ws, size_t ws_size,
                              hipStream_t stream) {
    const float* x  = (const float*)d_in[0];
    const int* src  = (const int*)d_in[1];
    const int* dst  = (const int*)d_in[2];
    const float* W1 = (const float*)d_in[3];
    const float* b1 = (const float*)d_in[4];
    const float* W2 = (const float*)d_in[5];
    const float* b2 = (const float*)d_in[6];
    const float* W3 = (const float*)d_in[7];
    const float* b3 = (const float*)d_in[8];
    float* out = (float*)d_out;

    const int n  = in_sizes[0] / 32;    // 100000
    const int nE = in_sizes[1];         // 1600000
    const int nbk = (n + RANGE - 1) >> RANGE_BITS;   // 782

    // workspace layout (words)
    float*    h1    = (float*)d_ws;                  // n*32
    float*    h2    = h1 + (size_t)n * 32;           // n*32
    unsigned* edata = (unsigned*)(h2 + (size_t)n * 32);  // nE
    int*      off   = (int*)(edata + nE);            // nbk+1
    int*      gcur  = off + nbk + 1;                 // nbk (also hist)
    size_t need = ((size_t)n * 64 + (size_t)nE + 2 * (size_t)nbk + 1) * 4;

    if (ws_size >= need && nbk <= MAXBK && n < (1 << 17)) {
        hipMemsetAsync(gcur, 0, (size_t)nbk * sizeof(int), stream);
        hist_kernel<<<128, 512, 0, stream>>>(dst, gcur, nE, nbk);
        scan_kernel<<<1, 1024, 0, stream>>>(gcur, off, gcur, nbk);
        fill_kernel<<<(nE + CHUNK - 1) / CHUNK, FILL_T, 0, stream>>>(src, dst, gcur, edata, nE, nbk);

        layer_kernel<32, true><<<nbk, LAYER_T, 0, stream>>>(x,  edata, off, W1, b1, h1, n);
        layer_kernel<32, true><<<nbk, LAYER_T, 0, stream>>>(h1, edata, off, W2, b2, h2, n);
        dense_kernel<32, 16><<<(n + 255) / 256, 256, 0, stream>>>(h2, W3, h1, n);  // t3 = h1
        agg16_kernel<<<nbk, LAYER_T, 0, stream>>>(h1, edata, off, b3, out, n);
    } else {
        const int BLK = 256;
        const int node_grid = (n + BLK - 1) / BLK;
        float* agg = h1;
        float* h   = h2;
        hipMemsetAsync(agg, 0, (size_t)n * 32 * sizeof(float), stream);
        scatter_kernel<32><<<((size_t)nE * 32 + BLK - 1) / BLK, BLK, 0, stream>>>(x, src, dst, agg, nE);
        dense_bias_kernel<32, 32, true><<<node_grid, BLK, 0, stream>>>(agg, W1, b1, h, n);
        hipMemsetAsync(agg, 0, (size_t)n * 32 * sizeof(float), stream);
        scatter_kernel<32><<<((size_t)nE * 32 + BLK - 1) / BLK, BLK, 0, stream>>>(h, src, dst, agg, nE);
        dense_bias_kernel<32, 32, true><<<node_grid, BLK, 0, stream>>>(agg, W2, b2, h, n);
        dense_kernel<32, 16><<<node_grid, BLK, 0, stream>>>(h, W3, agg, n);
        init_out_kernel<<<(n * 16 + BLK - 1) / BLK, BLK, 0, stream>>>(out, b3, n * 16);
        scatter_kernel<16><<<((size_t)nE * 16 + BLK - 1) / BLK, BLK, 0, stream>>>(agg, src, dst, out, nE);
    }
}

// Round 5
// 180.254 us; speedup vs baseline: 8.5275x; 5.0720x over previous
//
#include <hip/hip_runtime.h>

// GCN3: partition edges by 128-node dst-buckets (two-pass chunked fill, low
// write amplification), counting-sort each bucket into a per-node CSR, then
// per layer run an atomic-free register-accumulating gather fused with the
// dense transform (+bias, +LeakyReLU). Layer 3 transforms first (32->16).

#define RANGE_BITS 7
#define RANGE      128                  // nodes per bucket
#define MAXBK      1024                 // max buckets supported by LDS tables
#define CHUNK      8192                 // edges per fill block
#define FILL_T     512
#define CSR_T      256

// ---------------- partition build ----------------

__global__ void hist_kernel(const int* __restrict__ dst, int* __restrict__ ghist,
                            int nE, int nbk) {
    __shared__ int h[MAXBK];
    const int tid = threadIdx.x;
    for (int i = tid; i < nbk; i += blockDim.x) h[i] = 0;
    __syncthreads();
    const int stride = gridDim.x * blockDim.x;
    for (int e = blockIdx.x * blockDim.x + tid; e < nE; e += stride)
        atomicAdd(&h[dst[e] >> RANGE_BITS], 1);
    __syncthreads();
    for (int i = tid; i < nbk; i += blockDim.x) {
        int c = h[i];
        if (c) atomicAdd(&ghist[i], c);
    }
}

// single block: exclusive scan of ghist -> boff[0..nbk], gcur = boff
__global__ void scan_kernel(int* __restrict__ ghist, int* __restrict__ boff,
                            int* __restrict__ gcur, int nbk) {
    __shared__ int lds[MAXBK];
    const int tid = threadIdx.x;
    for (int i = tid; i < nbk; i += blockDim.x) lds[i] = ghist[i];
    __syncthreads();
    for (int o = 1; o < nbk; o <<= 1) {
        int v = (tid >= o && tid < nbk) ? lds[tid - o] : 0;
        __syncthreads();
        if (tid < nbk) lds[tid] += v;
        __syncthreads();
    }
    if (tid < nbk) {
        int ex = (tid == 0) ? 0 : lds[tid - 1];
        boff[tid] = ex;
        gcur[tid] = ex;
        if (tid == nbk - 1) boff[nbk] = lds[tid];
    }
}

// two-pass chunked fill -> bucketed edata, packed (dloc<<17)|src
__global__ __launch_bounds__(FILL_T)
void fill_kernel(const int* __restrict__ src, const int* __restrict__ dst,
                 int* __restrict__ gcur, unsigned* __restrict__ edata,
                 int nE, int nbk) {
    __shared__ int cnt[MAXBK];
    __shared__ int base[MAXBK];
    const int tid = threadIdx.x;
    const int c0 = blockIdx.x * CHUNK;
    const int c1 = min(c0 + CHUNK, nE);
    for (int i = tid; i < nbk; i += FILL_T) cnt[i] = 0;
    __syncthreads();
    for (int e = c0 + tid; e < c1; e += FILL_T)
        atomicAdd(&cnt[dst[e] >> RANGE_BITS], 1);
    __syncthreads();
    for (int i = tid; i < nbk; i += FILL_T) {
        int c = cnt[i];
        base[i] = c ? atomicAdd(&gcur[i], c) : 0;
        cnt[i] = 0;
    }
    __syncthreads();
    for (int e = c0 + tid; e < c1; e += FILL_T) {
        int d = dst[e];
        int bk = d >> RANGE_BITS;
        int pos = base[bk] + atomicAdd(&cnt[bk], 1);
        edata[pos] = ((unsigned)(d & (RANGE - 1)) << 17) | (unsigned)src[e];
    }
}

// per-bucket counting sort (global re-read, no staging cap) -> perm + off
__global__ __launch_bounds__(CSR_T)
void csr_kernel(const unsigned* __restrict__ edata, const int* __restrict__ boff,
                int* __restrict__ off, int* __restrict__ perm, int n, int nE) {
    __shared__ int hist[RANGE];
    __shared__ int loff[RANGE];
    __shared__ int cur[RANGE];
    const int tid = threadIdx.x;
    const int rid = blockIdx.x;
    const int e0  = boff[rid];
    const int cnt = boff[rid + 1] - e0;

    if (tid < RANGE) hist[tid] = 0;
    __syncthreads();
    for (int i = tid; i < cnt; i += CSR_T)
        atomicAdd(&hist[edata[e0 + i] >> 17], 1);
    __syncthreads();
    if (tid < RANGE) loff[tid] = hist[tid];
    __syncthreads();
    for (int o = 1; o < RANGE; o <<= 1) {
        int v = (tid >= o && tid < RANGE) ? loff[tid - o] : 0;
        __syncthreads();
        if (tid < RANGE) loff[tid] += v;
        __syncthreads();
    }
    if (tid < RANGE) {
        int ex = loff[tid] - hist[tid];          // exclusive
        cur[tid] = ex;
        int node = (rid << RANGE_BITS) + tid;
        if (node < n) off[node] = e0 + ex;
    }
    if (tid == 0 && rid == gridDim.x - 1) off[n] = nE;
    __syncthreads();
    for (int i = tid; i < cnt; i += CSR_T) {
        unsigned p = edata[e0 + i];
        int dl = (int)(p >> 17);
        int pos = atomicAdd(&cur[dl], 1);
        perm[e0 + pos] = (int)(p & 0x1ffffu);
    }
}

// ---------------- fused gather + dense (layers 1,2) ----------------

template <bool RELU>
__global__ __launch_bounds__(256)
void gather_dense_kernel(const float* __restrict__ t,     // [n][32]
                         const int* __restrict__ perm,
                         const int* __restrict__ off,
                         const float* __restrict__ W,     // [32][32]
                         const float* __restrict__ b,
                         float* __restrict__ out,         // [n][32]
                         int n) {
    __shared__ float rowbuf[8][33];                       // pad: conflict-free
    const int gid  = blockIdx.x * 256 + threadIdx.x;
    const int node = gid >> 5;
    const int f    = gid & 31;
    const int g    = threadIdx.x >> 5;

    float wcol[32];
#pragma unroll
    for (int k = 0; k < 32; ++k) wcol[k] = W[(k << 5) + f];  // lane's W column
    const float bias = b[f];

    if (node >= n) return;
    const int o = off[node];
    const int d = off[node + 1] - o;
    const int* __restrict__ pp = perm + o;

    float acc = 0.0f;
    int i = 0;
    for (; i + 3 < d; i += 4) {
        int s0 = pp[i], s1 = pp[i + 1], s2 = pp[i + 2], s3 = pp[i + 3];
        float v0 = t[(s0 << 5) + f];
        float v1 = t[(s1 << 5) + f];
        float v2 = t[(s2 << 5) + f];
        float v3 = t[(s3 << 5) + f];
        acc += v0; acc += v1; acc += v2; acc += v3;
    }
    for (; i < d; ++i) acc += t[(pp[i] << 5) + f];

    rowbuf[g][f] = acc;            // wave-local exchange (no barrier needed)
    float r = bias;
#pragma unroll
    for (int k = 0; k < 32; ++k) r += rowbuf[g][k] * wcol[k];
    if (RELU) r = r >= 0.0f ? r : 0.1f * r;
    out[(node << 5) + f] = r;
}

// ---------------- layer 3: dense 32->16, then 16-wide gather ----------------

template <int IN, int OUT>
__global__ void dense_kernel(const float* __restrict__ in,
                             const float* __restrict__ W,
                             float* __restrict__ out, int n) {
    __shared__ float sW[IN * OUT];
    for (int i = threadIdx.x; i < IN * OUT; i += blockDim.x) sW[i] = W[i];
    __syncthreads();
    int node = blockIdx.x * blockDim.x + threadIdx.x;
    if (node >= n) return;
    float row[IN];
    const float4* rp = (const float4*)(in + (size_t)node * IN);
#pragma unroll
    for (int k4 = 0; k4 < IN / 4; ++k4) {
        float4 v = rp[k4];
        row[k4 * 4] = v.x; row[k4 * 4 + 1] = v.y;
        row[k4 * 4 + 2] = v.z; row[k4 * 4 + 3] = v.w;
    }
    float acc[OUT];
#pragma unroll
    for (int j = 0; j < OUT; ++j) acc[j] = 0.0f;
#pragma unroll
    for (int k = 0; k < IN; ++k) {
        float a = row[k];
#pragma unroll
        for (int j = 0; j < OUT; ++j) acc[j] += a * sW[k * OUT + j];
    }
    float4* op = (float4*)(out + (size_t)node * OUT);
#pragma unroll
    for (int j4 = 0; j4 < OUT / 4; ++j4) {
        float4 v;
        v.x = acc[j4 * 4]; v.y = acc[j4 * 4 + 1];
        v.z = acc[j4 * 4 + 2]; v.w = acc[j4 * 4 + 3];
        op[j4] = v;
    }
}

__global__ __launch_bounds__(256)
void gather16_kernel(const float* __restrict__ t3,       // [n][16]
                     const int* __restrict__ perm,
                     const int* __restrict__ off,
                     const float* __restrict__ b,        // [16]
                     float* __restrict__ out,            // [n][16]
                     int n) {
    const int gid  = blockIdx.x * 256 + threadIdx.x;
    const int node = gid >> 4;
    const int j    = gid & 15;
    if (node >= n) return;
    const int o = off[node];
    const int d = off[node + 1] - o;
    const int* __restrict__ pp = perm + o;
    float acc = b[j];
    int i = 0;
    for (; i + 3 < d; i += 4) {
        int s0 = pp[i], s1 = pp[i + 1], s2 = pp[i + 2], s3 = pp[i + 3];
        float v0 = t3[(s0 << 4) + j];
        float v1 = t3[(s1 << 4) + j];
        float v2 = t3[(s2 << 4) + j];
        float v3 = t3[(s3 << 4) + j];
        acc += v0; acc += v1; acc += v2; acc += v3;
    }
    for (; i < d; ++i) acc += t3[(pp[i] << 4) + j];
    out[(node << 4) + j] = acc;
}

// ---------------- fallback: atomic scatter path ----------------

template <int F>
__global__ void scatter_kernel(const float* __restrict__ h, const int* __restrict__ src,
                               const int* __restrict__ dst, float* __restrict__ agg,
                               int n_edges) {
    int gid = blockIdx.x * blockDim.x + threadIdx.x;
    int e = gid / F, f = gid & (F - 1);
    if (e >= n_edges) return;
    unsafeAtomicAdd(&agg[(size_t)dst[e] * F + f], h[(size_t)src[e] * F + f]);
}

template <int IN, int OUT, bool RELU>
__global__ void dense_bias_kernel(const float* __restrict__ in, const float* __restrict__ W,
                                  const float* __restrict__ b, float* __restrict__ out, int n) {
    __shared__ float sW[IN * OUT];
    __shared__ float sb[OUT];
    for (int i = threadIdx.x; i < IN * OUT; i += blockDim.x) sW[i] = W[i];
    for (int i = threadIdx.x; i < OUT; i += blockDim.x) sb[i] = b[i];
    __syncthreads();
    int node = blockIdx.x * blockDim.x + threadIdx.x;
    if (node >= n) return;
    float acc[OUT];
#pragma unroll
    for (int j = 0; j < OUT; ++j) acc[j] = sb[j];
#pragma unroll
    for (int k = 0; k < IN; ++k) {
        float a = in[(size_t)node * IN + k];
#pragma unroll
        for (int j = 0; j < OUT; ++j) acc[j] += a * sW[k * OUT + j];
    }
#pragma unroll
    for (int j = 0; j < OUT; ++j) {
        float v = acc[j];
        out[(size_t)node * OUT + j] = (RELU && v < 0.0f) ? 0.1f * v : v;
    }
}

__global__ void init_out_kernel(float* __restrict__ out, const float* __restrict__ b,
                                int total) {
    int gid = blockIdx.x * blockDim.x + threadIdx.x;
    if (gid < total) out[gid] = b[gid & 15];
}

// ---------------- launch ----------------

extern "C" void kernel_launch(void* const* d_in, const int* in_sizes, int n_in,
                              void* d_out, int out_size, void* d_ws, size_t ws_size,
                              hipStream_t stream) {
    const float* x  = (const float*)d_in[0];
    const int* src  = (const int*)d_in[1];
    const int* dst  = (const int*)d_in[2];
    const float* W1 = (const float*)d_in[3];
    const float* b1 = (const float*)d_in[4];
    const float* W2 = (const float*)d_in[5];
    const float* b2 = (const float*)d_in[6];
    const float* W3 = (const float*)d_in[7];
    const float* b3 = (const float*)d_in[8];
    float* out = (float*)d_out;

    const int n  = in_sizes[0] / 32;    // 100000
    const int nE = in_sizes[1];         // 1600000
    const int nbk = (n + RANGE - 1) >> RANGE_BITS;   // 782

    // workspace layout (4-byte words)
    float*    h1    = (float*)d_ws;                      // n*32
    float*    h2    = h1 + (size_t)n * 32;               // n*32
    unsigned* edata = (unsigned*)(h2 + (size_t)n * 32);  // nE
    int*      perm  = (int*)(edata + nE);                // nE
    int*      off   = perm + nE;                         // n+1
    int*      boff  = off + n + 1;                       // nbk+1
    int*      gcur  = boff + nbk + 1;                    // nbk
    size_t need = ((size_t)n * 64 + 2 * (size_t)nE + (size_t)n + 2 * (size_t)nbk + 2) * 4;

    if (ws_size >= need && nbk <= MAXBK && n < (1 << 17)) {
        hipMemsetAsync(gcur, 0, (size_t)nbk * sizeof(int), stream);
        hist_kernel<<<128, 512, 0, stream>>>(dst, gcur, nE, nbk);
        scan_kernel<<<1, 1024, 0, stream>>>(gcur, boff, gcur, nbk);
        fill_kernel<<<(nE + CHUNK - 1) / CHUNK, FILL_T, 0, stream>>>(src, dst, gcur, edata, nE, nbk);
        csr_kernel<<<nbk, CSR_T, 0, stream>>>(edata, boff, off, perm, n, nE);

        const int g32 = (n * 32 + 255) / 256;
        const int g16 = (n * 16 + 255) / 256;
        gather_dense_kernel<true><<<g32, 256, 0, stream>>>(x,  perm, off, W1, b1, h1, n);
        gather_dense_kernel<true><<<g32, 256, 0, stream>>>(h1, perm, off, W2, b2, h2, n);
        dense_kernel<32, 16><<<(n + 255) / 256, 256, 0, stream>>>(h2, W3, h1, n);   // t3 = h1
        gather16_kernel<<<g16, 256, 0, stream>>>(h1, perm, off, b3, out, n);
    } else {
        const int BLK = 256;
        const int node_grid = (n + BLK - 1) / BLK;
        float* agg = h1;
        float* h   = h2;
        hipMemsetAsync(agg, 0, (size_t)n * 32 * sizeof(float), stream);
        scatter_kernel<32><<<((size_t)nE * 32 + BLK - 1) / BLK, BLK, 0, stream>>>(x, src, dst, agg, nE);
        dense_bias_kernel<32, 32, true><<<node_grid, BLK, 0, stream>>>(agg, W1, b1, h, n);
        hipMemsetAsync(agg, 0, (size_t)n * 32 * sizeof(float), stream);
        scatter_kernel<32><<<((size_t)nE * 32 + BLK - 1) / BLK, BLK, 0, stream>>>(h, src, dst, agg, nE);
        dense_bias_kernel<32, 32, true><<<node_grid, BLK, 0, stream>>>(agg, W2, b2, h, n);
        dense_kernel<32, 16><<<node_grid, BLK, 0, stream>>>(h, W3, agg, n);
        init_out_kernel<<<(n * 16 + BLK - 1) / BLK, BLK, 0, stream>>>(out, b3, n * 16);
        scatter_kernel<16><<<((size_t)nE * 16 + BLK - 1) / BLK, BLK, 0, stream>>>(agg, src, dst, out, nE);
    }
}

// Round 6
// 163.422 us; speedup vs baseline: 9.4058x; 1.1030x over previous
//
#include <hip/hip_runtime.h>

// GCN3: bucket-partition edges (low write-amp), per-bucket counting sort ->
// CSR, then atomic-free register-accumulating gathers fused with the dense
// transforms. Gathers use cooperative shuffle-distributed perm indices and
// 16-deep load unrolling for memory-level parallelism. Layer 2 fuses the
// 32->16 W3 transform into its epilogue; layer 3 is a 16-wide gather.

#define RANGE_BITS 7
#define RANGE      128                  // nodes per bucket
#define MAXBK      1024                 // max buckets supported by LDS tables
#define CHUNK      8192                 // edges per fill block
#define FILL_T     512
#define CSR_T      256
#define CSR_CAP    4096                 // LDS staging capacity (edges/bucket)

// ---------------- partition build ----------------

__global__ void hist_kernel(const int* __restrict__ dst, int* __restrict__ ghist,
                            int nE, int nbk) {
    __shared__ int h[MAXBK];
    const int tid = threadIdx.x;
    for (int i = tid; i < nbk; i += blockDim.x) h[i] = 0;
    __syncthreads();
    const int stride = gridDim.x * blockDim.x;
    for (int e = blockIdx.x * blockDim.x + tid; e < nE; e += stride)
        atomicAdd(&h[dst[e] >> RANGE_BITS], 1);
    __syncthreads();
    for (int i = tid; i < nbk; i += blockDim.x) {
        int c = h[i];
        if (c) atomicAdd(&ghist[i], c);
    }
}

__global__ void scan_kernel(int* __restrict__ ghist, int* __restrict__ boff,
                            int* __restrict__ gcur, int nbk) {
    __shared__ int lds[MAXBK];
    const int tid = threadIdx.x;
    for (int i = tid; i < nbk; i += blockDim.x) lds[i] = ghist[i];
    __syncthreads();
    for (int o = 1; o < nbk; o <<= 1) {
        int v = (tid >= o && tid < nbk) ? lds[tid - o] : 0;
        __syncthreads();
        if (tid < nbk) lds[tid] += v;
        __syncthreads();
    }
    if (tid < nbk) {
        int ex = (tid == 0) ? 0 : lds[tid - 1];
        boff[tid] = ex;
        gcur[tid] = ex;
        if (tid == nbk - 1) boff[nbk] = lds[tid];
    }
}

__global__ __launch_bounds__(FILL_T)
void fill_kernel(const int* __restrict__ src, const int* __restrict__ dst,
                 int* __restrict__ gcur, unsigned* __restrict__ edata,
                 int nE, int nbk) {
    __shared__ int cnt[MAXBK];
    __shared__ int base[MAXBK];
    const int tid = threadIdx.x;
    const int c0 = blockIdx.x * CHUNK;
    const int c1 = min(c0 + CHUNK, nE);
    for (int i = tid; i < nbk; i += FILL_T) cnt[i] = 0;
    __syncthreads();
    for (int e = c0 + tid; e < c1; e += FILL_T)
        atomicAdd(&cnt[dst[e] >> RANGE_BITS], 1);
    __syncthreads();
    for (int i = tid; i < nbk; i += FILL_T) {
        int c = cnt[i];
        base[i] = c ? atomicAdd(&gcur[i], c) : 0;
        cnt[i] = 0;
    }
    __syncthreads();
    for (int e = c0 + tid; e < c1; e += FILL_T) {
        int d = dst[e];
        int bk = d >> RANGE_BITS;
        int pos = base[bk] + atomicAdd(&cnt[bk], 1);
        edata[pos] = ((unsigned)(d & (RANGE - 1)) << 17) | (unsigned)src[e];
    }
}

// per-bucket counting sort with LDS staging -> perm + off
__global__ __launch_bounds__(CSR_T)
void csr_kernel(const unsigned* __restrict__ edata, const int* __restrict__ boff,
                int* __restrict__ off, int* __restrict__ perm, int n, int nE) {
    __shared__ int hist[RANGE];
    __shared__ int loff[RANGE];
    __shared__ int cur[RANGE];
    __shared__ unsigned stage[CSR_CAP];
    const int tid = threadIdx.x;
    const int rid = blockIdx.x;
    const int e0  = boff[rid];
    const int cnt = boff[rid + 1] - e0;
    const bool fits = cnt <= CSR_CAP;

    if (tid < RANGE) hist[tid] = 0;
    __syncthreads();
    for (int i = tid; i < cnt; i += CSR_T) {
        unsigned p = edata[e0 + i];
        if (fits) stage[i] = p;
        atomicAdd(&hist[p >> 17], 1);
    }
    __syncthreads();
    if (tid < RANGE) loff[tid] = hist[tid];
    __syncthreads();
    for (int o = 1; o < RANGE; o <<= 1) {
        int v = (tid >= o && tid < RANGE) ? loff[tid - o] : 0;
        __syncthreads();
        if (tid < RANGE) loff[tid] += v;
        __syncthreads();
    }
    if (tid < RANGE) {
        int ex = loff[tid] - hist[tid];
        cur[tid] = ex;
        int node = (rid << RANGE_BITS) + tid;
        if (node < n) off[node] = e0 + ex;
    }
    if (tid == 0 && rid == gridDim.x - 1) off[n] = nE;
    __syncthreads();
    for (int i = tid; i < cnt; i += CSR_T) {
        unsigned p = fits ? stage[i] : edata[e0 + i];
        int pos = atomicAdd(&cur[p >> 17], 1);
        perm[e0 + pos] = (int)(p & 0x1ffffu);
    }
}

// ---------------- fused gather + dense ----------------
// 32 lanes per node. Cooperative perm load (lane f loads perm[o+f]) + __shfl
// distribution; 16-deep unrolled feature gathers. Epilogue: LDS row exchange
// -> dense 32xFOUT + bias + LeakyReLU. FUSE3: additionally apply W3 (32->16)
// and emit the 16-wide t3 row instead of the 32-wide h row.

template <bool RELU, bool FUSE3>
__global__ __launch_bounds__(256)
void gather_dense_kernel(const float* __restrict__ t,     // [n][32]
                         const int* __restrict__ perm,
                         const int* __restrict__ off,
                         const float* __restrict__ W,     // [32][32]
                         const float* __restrict__ b,     // [32]
                         const float* __restrict__ W3,    // [32][16] (FUSE3)
                         float* __restrict__ out,         // [n][32] or [n][16]
                         int n) {
    __shared__ float rowbuf[8][33];
    __shared__ float rowbuf2[8][33];
    __shared__ float sW3[32 * 16];
    if (FUSE3) {
        for (int i = threadIdx.x; i < 32 * 16; i += 256) sW3[i] = W3[i];
        __syncthreads();
    }

    const int gid  = blockIdx.x * 256 + threadIdx.x;
    const int node = gid >> 5;
    const int f    = gid & 31;
    const int g    = threadIdx.x >> 5;
    if (node >= n) return;

    const int o = off[node];
    const int d = off[node + 1] - o;
    const int* __restrict__ pp = perm + o;

    float acc = 0.0f;
    for (int base = 0; base < d; base += 32) {
        const int rem = d - base;
        const int m = rem < 32 ? rem : 32;
        int pidx = (f < m) ? pp[base + f] : 0;   // 1 coalesced load / 32 edges
        int i = 0;
        for (; i + 15 < m; i += 16) {
            int s[16]; float v[16];
#pragma unroll
            for (int u = 0; u < 16; ++u) s[u] = __shfl(pidx, i + u, 32);
#pragma unroll
            for (int u = 0; u < 16; ++u) v[u] = t[(s[u] << 5) + f];
#pragma unroll
            for (int u = 0; u < 16; ++u) acc += v[u];
        }
        for (; i + 3 < m; i += 4) {
            int s[4]; float v[4];
#pragma unroll
            for (int u = 0; u < 4; ++u) s[u] = __shfl(pidx, i + u, 32);
#pragma unroll
            for (int u = 0; u < 4; ++u) v[u] = t[(s[u] << 5) + f];
#pragma unroll
            for (int u = 0; u < 4; ++u) acc += v[u];
        }
        for (; i < m; ++i) acc += t[(__shfl(pidx, i, 32) << 5) + f];
    }

    // dense epilogue: exchange acc row through LDS (wave-local, in-order)
    rowbuf[g][f] = acc;
    float r = b[f];
#pragma unroll
    for (int k = 0; k < 32; ++k) r += rowbuf[g][k] * W[(k << 5) + f];
    if (RELU) r = r >= 0.0f ? r : 0.1f * r;

    if (!FUSE3) {
        out[(node << 5) + f] = r;
    } else {
        rowbuf2[g][f] = r;
        const int j = f & 15;
        float t3 = 0.0f;
#pragma unroll
        for (int k = 0; k < 32; ++k) t3 += rowbuf2[g][k] * sW3[(k << 4) + j];
        if (f < 16) out[(node << 4) + f] = t3;
    }
}

// layer 3: 16-wide gather of pre-transformed rows, bias-initialized
__global__ __launch_bounds__(256)
void gather16_kernel(const float* __restrict__ t3,       // [n][16]
                     const int* __restrict__ perm,
                     const int* __restrict__ off,
                     const float* __restrict__ b,        // [16]
                     float* __restrict__ out,            // [n][16]
                     int n) {
    const int gid  = blockIdx.x * 256 + threadIdx.x;
    const int node = gid >> 4;
    const int j    = gid & 15;
    if (node >= n) return;
    const int o = off[node];
    const int d = off[node + 1] - o;
    const int* __restrict__ pp = perm + o;
    float acc = b[j];
    for (int base = 0; base < d; base += 16) {
        const int rem = d - base;
        const int m = rem < 16 ? rem : 16;
        int pidx = (j < m) ? pp[base + j] : 0;
        int i = 0;
        for (; i + 7 < m; i += 8) {
            int s[8]; float v[8];
#pragma unroll
            for (int u = 0; u < 8; ++u) s[u] = __shfl(pidx, i + u, 16);
#pragma unroll
            for (int u = 0; u < 8; ++u) v[u] = t3[(s[u] << 4) + j];
#pragma unroll
            for (int u = 0; u < 8; ++u) acc += v[u];
        }
        for (; i < m; ++i) acc += t3[(__shfl(pidx, i, 16) << 4) + j];
    }
    out[(node << 4) + j] = acc;
}

// ---------------- fallback: atomic scatter path ----------------

template <int F>
__global__ void scatter_kernel(const float* __restrict__ h, const int* __restrict__ src,
                               const int* __restrict__ dst, float* __restrict__ agg,
                               int n_edges) {
    int gid = blockIdx.x * blockDim.x + threadIdx.x;
    int e = gid / F, f = gid & (F - 1);
    if (e >= n_edges) return;
    unsafeAtomicAdd(&agg[(size_t)dst[e] * F + f], h[(size_t)src[e] * F + f]);
}

template <int IN, int OUT, bool RELU>
__global__ void dense_bias_kernel(const float* __restrict__ in, const float* __restrict__ W,
                                  const float* __restrict__ b, float* __restrict__ out, int n) {
    __shared__ float sW[IN * OUT];
    __shared__ float sb[OUT];
    for (int i = threadIdx.x; i < IN * OUT; i += blockDim.x) sW[i] = W[i];
    for (int i = threadIdx.x; i < OUT; i += blockDim.x) sb[i] = b[i];
    __syncthreads();
    int node = blockIdx.x * blockDim.x + threadIdx.x;
    if (node >= n) return;
    float acc[OUT];
#pragma unroll
    for (int j = 0; j < OUT; ++j) acc[j] = sb[j];
#pragma unroll
    for (int k = 0; k < IN; ++k) {
        float a = in[(size_t)node * IN + k];
#pragma unroll
        for (int j = 0; j < OUT; ++j) acc[j] += a * sW[k * OUT + j];
    }
#pragma unroll
    for (int j = 0; j < OUT; ++j) {
        float v = acc[j];
        out[(size_t)node * OUT + j] = (RELU && v < 0.0f) ? 0.1f * v : v;
    }
}

template <int IN, int OUT>
__global__ void dense_kernel(const float* __restrict__ in, const float* __restrict__ W,
                             float* __restrict__ out, int n) {
    __shared__ float sW[IN * OUT];
    for (int i = threadIdx.x; i < IN * OUT; i += blockDim.x) sW[i] = W[i];
    __syncthreads();
    int node = blockIdx.x * blockDim.x + threadIdx.x;
    if (node >= n) return;
    float acc[OUT];
#pragma unroll
    for (int j = 0; j < OUT; ++j) acc[j] = 0.0f;
#pragma unroll
    for (int k = 0; k < IN; ++k) {
        float a = in[(size_t)node * IN + k];
#pragma unroll
        for (int j = 0; j < OUT; ++j) acc[j] += a * sW[k * OUT + j];
    }
#pragma unroll
    for (int j = 0; j < OUT; ++j) out[(size_t)node * OUT + j] = acc[j];
}

__global__ void init_out_kernel(float* __restrict__ out, const float* __restrict__ b,
                                int total) {
    int gid = blockIdx.x * blockDim.x + threadIdx.x;
    if (gid < total) out[gid] = b[gid & 15];
}

// ---------------- launch ----------------

extern "C" void kernel_launch(void* const* d_in, const int* in_sizes, int n_in,
                              void* d_out, int out_size, void* d_ws, size_t ws_size,
                              hipStream_t stream) {
    const float* x  = (const float*)d_in[0];
    const int* src  = (const int*)d_in[1];
    const int* dst  = (const int*)d_in[2];
    const float* W1 = (const float*)d_in[3];
    const float* b1 = (const float*)d_in[4];
    const float* W2 = (const float*)d_in[5];
    const float* b2 = (const float*)d_in[6];
    const float* W3 = (const float*)d_in[7];
    const float* b3 = (const float*)d_in[8];
    float* out = (float*)d_out;

    const int n  = in_sizes[0] / 32;    // 100000
    const int nE = in_sizes[1];         // 1600000
    const int nbk = (n + RANGE - 1) >> RANGE_BITS;   // 782

    // workspace layout (4-byte words)
    float*    h1    = (float*)d_ws;                      // n*32
    float*    h2    = h1 + (size_t)n * 32;               // n*32 (t3 uses n*16)
    unsigned* edata = (unsigned*)(h2 + (size_t)n * 32);  // nE
    int*      perm  = (int*)(edata + nE);                // nE
    int*      off   = perm + nE;                         // n+1
    int*      boff  = off + n + 1;                       // nbk+1
    int*      gcur  = boff + nbk + 1;                    // nbk
    size_t need = ((size_t)n * 64 + 2 * (size_t)nE + (size_t)n + 2 * (size_t)nbk + 2) * 4;

    if (ws_size >= need && nbk <= MAXBK && n < (1 << 17)) {
        hipMemsetAsync(gcur, 0, (size_t)nbk * sizeof(int), stream);
        hist_kernel<<<256, 512, 0, stream>>>(dst, gcur, nE, nbk);
        scan_kernel<<<1, 1024, 0, stream>>>(gcur, boff, gcur, nbk);
        fill_kernel<<<(nE + CHUNK - 1) / CHUNK, FILL_T, 0, stream>>>(src, dst, gcur, edata, nE, nbk);
        csr_kernel<<<nbk, CSR_T, 0, stream>>>(edata, boff, off, perm, n, nE);

        const int g32 = (n * 32 + 255) / 256;
        const int g16 = (n * 16 + 255) / 256;
        // layer 1: h1 = leaky(agg(x) @ W1 + b1)
        gather_dense_kernel<true, false><<<g32, 256, 0, stream>>>(x, perm, off, W1, b1, nullptr, h1, n);
        // layer 2 fused with W3: t3 (in h2) = leaky(agg(h1) @ W2 + b2) @ W3
        gather_dense_kernel<true, true><<<g32, 256, 0, stream>>>(h1, perm, off, W2, b2, W3, h2, n);
        // layer 3: out = agg(t3) + b3
        gather16_kernel<<<g16, 256, 0, stream>>>(h2, perm, off, b3, out, n);
    } else {
        const int BLK = 256;
        const int node_grid = (n + BLK - 1) / BLK;
        float* agg = h1;
        float* h   = h2;
        hipMemsetAsync(agg, 0, (size_t)n * 32 * sizeof(float), stream);
        scatter_kernel<32><<<((size_t)nE * 32 + BLK - 1) / BLK, BLK, 0, stream>>>(x, src, dst, agg, nE);
        dense_bias_kernel<32, 32, true><<<node_grid, BLK, 0, stream>>>(agg, W1, b1, h, n);
        hipMemsetAsync(agg, 0, (size_t)n * 32 * sizeof(float), stream);
        scatter_kernel<32><<<((size_t)nE * 32 + BLK - 1) / BLK, BLK, 0, stream>>>(h, src, dst, agg, nE);
        dense_bias_kernel<32, 32, true><<<node_grid, BLK, 0, stream>>>(agg, W2, b2, h, n);
        dense_kernel<32, 16><<<node_grid, BLK, 0, stream>>>(h, W3, agg, n);
        init_out_kernel<<<(n * 16 + BLK - 1) / BLK, BLK, 0, stream>>>(out, b3, n * 16);
        scatter_kernel<16><<<((size_t)nE * 16 + BLK - 1) / BLK, BLK, 0, stream>>>(agg, src, dst, out, nE);
    }
}

// Round 7
// 158.749 us; speedup vs baseline: 9.6827x; 1.0294x over previous
//
#include <hip/hip_runtime.h>

// GCN3: bucket-partition edges -> per-bucket counting sort -> CSR, then
// atomic-free register-accumulating gathers fused with the dense transforms.
// Gathered feature tables (x, h1, t3) are stored as bf16 (RNE) to halve the
// compulsory per-XCD L2-miss traffic of the random row gathers; all
// accumulation and dense math remain fp32. Layer 2 fuses the 32->16 W3
// transform; layer 3 is a 16-wide bf16 gather writing fp32 output.

#define RANGE_BITS 7
#define RANGE      128                  // nodes per bucket
#define MAXBK      1024                 // max buckets supported by LDS tables
#define CHUNK      8192                 // edges per fill block
#define FILL_T     512
#define CSR_T      256
#define CSR_CAP    4096                 // LDS staging capacity (edges/bucket)

typedef unsigned short ushort_t;

__device__ __forceinline__ ushort_t f32_to_bf16(float x) {
    unsigned u = __float_as_uint(x);
    u += 0x7fffu + ((u >> 16) & 1u);    // round to nearest even
    return (ushort_t)(u >> 16);
}
__device__ __forceinline__ float bf16_to_f32(ushort_t h) {
    return __uint_as_float(((unsigned)h) << 16);
}

// ---------------- partition build ----------------

__global__ void hist_kernel(const int* __restrict__ dst, int* __restrict__ ghist,
                            int nE, int nbk) {
    __shared__ int h[MAXBK];
    const int tid = threadIdx.x;
    for (int i = tid; i < nbk; i += blockDim.x) h[i] = 0;
    __syncthreads();
    const int stride = gridDim.x * blockDim.x;
    for (int e = blockIdx.x * blockDim.x + tid; e < nE; e += stride)
        atomicAdd(&h[dst[e] >> RANGE_BITS], 1);
    __syncthreads();
    for (int i = tid; i < nbk; i += blockDim.x) {
        int c = h[i];
        if (c) atomicAdd(&ghist[i], c);
    }
}

__global__ void scan_kernel(int* __restrict__ ghist, int* __restrict__ boff,
                            int* __restrict__ gcur, int nbk) {
    __shared__ int lds[MAXBK];
    const int tid = threadIdx.x;
    for (int i = tid; i < nbk; i += blockDim.x) lds[i] = ghist[i];
    __syncthreads();
    for (int o = 1; o < nbk; o <<= 1) {
        int v = (tid >= o && tid < nbk) ? lds[tid - o] : 0;
        __syncthreads();
        if (tid < nbk) lds[tid] += v;
        __syncthreads();
    }
    if (tid < nbk) {
        int ex = (tid == 0) ? 0 : lds[tid - 1];
        boff[tid] = ex;
        gcur[tid] = ex;
        if (tid == nbk - 1) boff[nbk] = lds[tid];
    }
}

__global__ __launch_bounds__(FILL_T)
void fill_kernel(const int* __restrict__ src, const int* __restrict__ dst,
                 int* __restrict__ gcur, unsigned* __restrict__ edata,
                 int nE, int nbk) {
    __shared__ int cnt[MAXBK];
    __shared__ int base[MAXBK];
    const int tid = threadIdx.x;
    const int c0 = blockIdx.x * CHUNK;
    const int c1 = min(c0 + CHUNK, nE);
    for (int i = tid; i < nbk; i += FILL_T) cnt[i] = 0;
    __syncthreads();
    for (int e = c0 + tid; e < c1; e += FILL_T)
        atomicAdd(&cnt[dst[e] >> RANGE_BITS], 1);
    __syncthreads();
    for (int i = tid; i < nbk; i += FILL_T) {
        int c = cnt[i];
        base[i] = c ? atomicAdd(&gcur[i], c) : 0;
        cnt[i] = 0;
    }
    __syncthreads();
    for (int e = c0 + tid; e < c1; e += FILL_T) {
        int d = dst[e];
        int bk = d >> RANGE_BITS;
        int pos = base[bk] + atomicAdd(&cnt[bk], 1);
        edata[pos] = ((unsigned)(d & (RANGE - 1)) << 17) | (unsigned)src[e];
    }
}

__global__ __launch_bounds__(CSR_T)
void csr_kernel(const unsigned* __restrict__ edata, const int* __restrict__ boff,
                int* __restrict__ off, int* __restrict__ perm, int n, int nE) {
    __shared__ int hist[RANGE];
    __shared__ int loff[RANGE];
    __shared__ int cur[RANGE];
    __shared__ unsigned stage[CSR_CAP];
    const int tid = threadIdx.x;
    const int rid = blockIdx.x;
    const int e0  = boff[rid];
    const int cnt = boff[rid + 1] - e0;
    const bool fits = cnt <= CSR_CAP;

    if (tid < RANGE) hist[tid] = 0;
    __syncthreads();
    for (int i = tid; i < cnt; i += CSR_T) {
        unsigned p = edata[e0 + i];
        if (fits) stage[i] = p;
        atomicAdd(&hist[p >> 17], 1);
    }
    __syncthreads();
    if (tid < RANGE) loff[tid] = hist[tid];
    __syncthreads();
    for (int o = 1; o < RANGE; o <<= 1) {
        int v = (tid >= o && tid < RANGE) ? loff[tid - o] : 0;
        __syncthreads();
        if (tid < RANGE) loff[tid] += v;
        __syncthreads();
    }
    if (tid < RANGE) {
        int ex = loff[tid] - hist[tid];
        cur[tid] = ex;
        int node = (rid << RANGE_BITS) + tid;
        if (node < n) off[node] = e0 + ex;
    }
    if (tid == 0 && rid == gridDim.x - 1) off[n] = nE;
    __syncthreads();
    for (int i = tid; i < cnt; i += CSR_T) {
        unsigned p = fits ? stage[i] : edata[e0 + i];
        int pos = atomicAdd(&cur[p >> 17], 1);
        perm[e0 + pos] = (int)(p & 0x1ffffu);
    }
}

// ---------------- fp32 -> bf16 table convert (8 elems/thread) ----------------

__global__ void cvt_bf16_kernel(const float* __restrict__ in,
                                ushort_t* __restrict__ out, int total8) {
    int i = blockIdx.x * blockDim.x + threadIdx.x;
    if (i >= total8) return;
    const float4* rp = (const float4*)(in + (size_t)i * 8);
    float4 a = rp[0], b = rp[1];
    ushort_t o[8];
    o[0] = f32_to_bf16(a.x); o[1] = f32_to_bf16(a.y);
    o[2] = f32_to_bf16(a.z); o[3] = f32_to_bf16(a.w);
    o[4] = f32_to_bf16(b.x); o[5] = f32_to_bf16(b.y);
    o[6] = f32_to_bf16(b.z); o[7] = f32_to_bf16(b.w);
    uint4* op = (uint4*)(out + (size_t)i * 8);
    uint4 v;
    v.x = (unsigned)o[0] | ((unsigned)o[1] << 16);
    v.y = (unsigned)o[2] | ((unsigned)o[3] << 16);
    v.z = (unsigned)o[4] | ((unsigned)o[5] << 16);
    v.w = (unsigned)o[6] | ((unsigned)o[7] << 16);
    op[0] = v;
}

// ---------------- fused gather + dense (bf16 tables, fp32 math) ----------------
// 32 lanes per node; cooperative perm load + __shfl distribution; 16-deep
// unrolled bf16 gathers (64B/edge). Epilogue: LDS row exchange -> dense
// 32x32 + bias + LeakyReLU; output bf16. FUSE3 additionally applies W3
// (32->16) and emits the bf16 t3 row.

template <bool FUSE3>
__global__ __launch_bounds__(256)
void gather_dense_kernel(const ushort_t* __restrict__ t,   // [n][32] bf16
                         const int* __restrict__ perm,
                         const int* __restrict__ off,
                         const float* __restrict__ W,      // [32][32]
                         const float* __restrict__ b,      // [32]
                         const float* __restrict__ W3,     // [32][16] (FUSE3)
                         ushort_t* __restrict__ out,       // [n][32] or [n][16] bf16
                         int n) {
    __shared__ float rowbuf[8][33];
    __shared__ float rowbuf2[8][33];
    __shared__ float sW3[32 * 16];
    if (FUSE3) {
        for (int i = threadIdx.x; i < 32 * 16; i += 256) sW3[i] = W3[i];
        __syncthreads();
    }

    const int gid  = blockIdx.x * 256 + threadIdx.x;
    const int node = gid >> 5;
    const int f    = gid & 31;
    const int g    = threadIdx.x >> 5;
    if (node >= n) return;

    const int o = off[node];
    const int d = off[node + 1] - o;
    const int* __restrict__ pp = perm + o;

    float acc = 0.0f;
    for (int base = 0; base < d; base += 32) {
        const int rem = d - base;
        const int m = rem < 32 ? rem : 32;
        int pidx = (f < m) ? pp[base + f] : 0;   // 1 coalesced load / 32 edges
        int i = 0;
        for (; i + 15 < m; i += 16) {
            int s[16]; ushort_t v[16];
#pragma unroll
            for (int u = 0; u < 16; ++u) s[u] = __shfl(pidx, i + u, 32);
#pragma unroll
            for (int u = 0; u < 16; ++u) v[u] = t[(s[u] << 5) + f];
#pragma unroll
            for (int u = 0; u < 16; ++u) acc += bf16_to_f32(v[u]);
        }
        for (; i + 3 < m; i += 4) {
            int s[4]; ushort_t v[4];
#pragma unroll
            for (int u = 0; u < 4; ++u) s[u] = __shfl(pidx, i + u, 32);
#pragma unroll
            for (int u = 0; u < 4; ++u) v[u] = t[(s[u] << 5) + f];
#pragma unroll
            for (int u = 0; u < 4; ++u) acc += bf16_to_f32(v[u]);
        }
        for (; i < m; ++i) acc += bf16_to_f32(t[(__shfl(pidx, i, 32) << 5) + f]);
    }

    rowbuf[g][f] = acc;                          // wave-local exchange
    float r = b[f];
#pragma unroll
    for (int k = 0; k < 32; ++k) r += rowbuf[g][k] * W[(k << 5) + f];
    r = r >= 0.0f ? r : 0.1f * r;                // LeakyReLU (both uses)

    if (!FUSE3) {
        out[(node << 5) + f] = f32_to_bf16(r);
    } else {
        rowbuf2[g][f] = r;
        const int j = f & 15;
        float t3 = 0.0f;
#pragma unroll
        for (int k = 0; k < 32; ++k) t3 += rowbuf2[g][k] * sW3[(k << 4) + j];
        if (f < 16) out[(node << 4) + f] = f32_to_bf16(t3);
    }
}

// layer 3: 16-wide gather of bf16 t3 rows, bias-initialized, fp32 output
__global__ __launch_bounds__(256)
void gather16_kernel(const ushort_t* __restrict__ t3,     // [n][16] bf16
                     const int* __restrict__ perm,
                     const int* __restrict__ off,
                     const float* __restrict__ b,         // [16]
                     float* __restrict__ out,             // [n][16] fp32
                     int n) {
    const int gid  = blockIdx.x * 256 + threadIdx.x;
    const int node = gid >> 4;
    const int j    = gid & 15;
    if (node >= n) return;
    const int o = off[node];
    const int d = off[node + 1] - o;
    const int* __restrict__ pp = perm + o;
    float acc = b[j];
    for (int base = 0; base < d; base += 16) {
        const int rem = d - base;
        const int m = rem < 16 ? rem : 16;
        int pidx = (j < m) ? pp[base + j] : 0;
        int i = 0;
        for (; i + 7 < m; i += 8) {
            int s[8]; ushort_t v[8];
#pragma unroll
            for (int u = 0; u < 8; ++u) s[u] = __shfl(pidx, i + u, 16);
#pragma unroll
            for (int u = 0; u < 8; ++u) v[u] = t3[(s[u] << 4) + j];
#pragma unroll
            for (int u = 0; u < 8; ++u) acc += bf16_to_f32(v[u]);
        }
        for (; i < m; ++i) acc += bf16_to_f32(t3[(__shfl(pidx, i, 16) << 4) + j]);
    }
    out[(node << 4) + j] = acc;
}

// ---------------- fallback: atomic scatter path (fp32) ----------------

template <int F>
__global__ void scatter_kernel(const float* __restrict__ h, const int* __restrict__ src,
                               const int* __restrict__ dst, float* __restrict__ agg,
                               int n_edges) {
    int gid = blockIdx.x * blockDim.x + threadIdx.x;
    int e = gid / F, f = gid & (F - 1);
    if (e >= n_edges) return;
    unsafeAtomicAdd(&agg[(size_t)dst[e] * F + f], h[(size_t)src[e] * F + f]);
}

template <int IN, int OUT, bool RELU>
__global__ void dense_bias_kernel(const float* __restrict__ in, const float* __restrict__ W,
                                  const float* __restrict__ b, float* __restrict__ out, int n) {
    __shared__ float sW[IN * OUT];
    __shared__ float sb[OUT];
    for (int i = threadIdx.x; i < IN * OUT; i += blockDim.x) sW[i] = W[i];
    for (int i = threadIdx.x; i < OUT; i += blockDim.x) sb[i] = b[i];
    __syncthreads();
    int node = blockIdx.x * blockDim.x + threadIdx.x;
    if (node >= n) return;
    float acc[OUT];
#pragma unroll
    for (int j = 0; j < OUT; ++j) acc[j] = sb[j];
#pragma unroll
    for (int k = 0; k < IN; ++k) {
        float a = in[(size_t)node * IN + k];
#pragma unroll
        for (int j = 0; j < OUT; ++j) acc[j] += a * sW[k * OUT + j];
    }
#pragma unroll
    for (int j = 0; j < OUT; ++j) {
        float v = acc[j];
        out[(size_t)node * OUT + j] = (RELU && v < 0.0f) ? 0.1f * v : v;
    }
}

template <int IN, int OUT>
__global__ void dense_kernel(const float* __restrict__ in, const float* __restrict__ W,
                             float* __restrict__ out, int n) {
    __shared__ float sW[IN * OUT];
    for (int i = threadIdx.x; i < IN * OUT; i += blockDim.x) sW[i] = W[i];
    __syncthreads();
    int node = blockIdx.x * blockDim.x + threadIdx.x;
    if (node >= n) return;
    float acc[OUT];
#pragma unroll
    for (int j = 0; j < OUT; ++j) acc[j] = 0.0f;
#pragma unroll
    for (int k = 0; k < IN; ++k) {
        float a = in[(size_t)node * IN + k];
#pragma unroll
        for (int j = 0; j < OUT; ++j) acc[j] += a * sW[k * OUT + j];
    }
#pragma unroll
    for (int j = 0; j < OUT; ++j) out[(size_t)node * OUT + j] = acc[j];
}

__global__ void init_out_kernel(float* __restrict__ out, const float* __restrict__ b,
                                int total) {
    int gid = blockIdx.x * blockDim.x + threadIdx.x;
    if (gid < total) out[gid] = b[gid & 15];
}

// ---------------- launch ----------------

extern "C" void kernel_launch(void* const* d_in, const int* in_sizes, int n_in,
                              void* d_out, int out_size, void* d_ws, size_t ws_size,
                              hipStream_t stream) {
    const float* x  = (const float*)d_in[0];
    const int* src  = (const int*)d_in[1];
    const int* dst  = (const int*)d_in[2];
    const float* W1 = (const float*)d_in[3];
    const float* b1 = (const float*)d_in[4];
    const float* W2 = (const float*)d_in[5];
    const float* b2 = (const float*)d_in[6];
    const float* W3 = (const float*)d_in[7];
    const float* b3 = (const float*)d_in[8];
    float* out = (float*)d_out;

    const int n  = in_sizes[0] / 32;    // 100000
    const int nE = in_sizes[1];         // 1600000
    const int nbk = (n + RANGE - 1) >> RANGE_BITS;   // 782

    // workspace layout (4-byte words)
    unsigned* wsw   = (unsigned*)d_ws;
    ushort_t* xb    = (ushort_t*)wsw;                      // n*32 bf16 = n*16 words
    ushort_t* h1b   = (ushort_t*)(wsw + (size_t)n * 16);   // n*32 bf16
    ushort_t* t3b   = (ushort_t*)(wsw + (size_t)n * 32);   // n*16 bf16 = n*8 words
    unsigned* edata = wsw + (size_t)n * 40;                // nE
    int*      perm  = (int*)(edata + nE);                  // nE
    int*      off   = perm + nE;                           // n+1
    int*      boff  = off + n + 1;                         // nbk+1
    int*      gcur  = boff + nbk + 1;                      // nbk
    size_t need = ((size_t)n * 40 + 2 * (size_t)nE + (size_t)n + 2 * (size_t)nbk + 2) * 4;

    if (ws_size >= need && nbk <= MAXBK && n < (1 << 17) && (n * 32) % 8 == 0) {
        hipMemsetAsync(gcur, 0, (size_t)nbk * sizeof(int), stream);
        hist_kernel<<<256, 512, 0, stream>>>(dst, gcur, nE, nbk);
        cvt_bf16_kernel<<<(n * 32 / 8 + 255) / 256, 256, 0, stream>>>(x, xb, n * 32 / 8);
        scan_kernel<<<1, 1024, 0, stream>>>(gcur, boff, gcur, nbk);
        fill_kernel<<<(nE + CHUNK - 1) / CHUNK, FILL_T, 0, stream>>>(src, dst, gcur, edata, nE, nbk);
        csr_kernel<<<nbk, CSR_T, 0, stream>>>(edata, boff, off, perm, n, nE);

        const int g32 = (n * 32 + 255) / 256;
        const int g16 = (n * 16 + 255) / 256;
        // layer 1: h1b = bf16(leaky(agg(xb) @ W1 + b1))
        gather_dense_kernel<false><<<g32, 256, 0, stream>>>(xb, perm, off, W1, b1, nullptr, h1b, n);
        // layer 2 (+W3 fused): t3b = bf16(leaky(agg(h1b) @ W2 + b2) @ W3)
        gather_dense_kernel<true><<<g32, 256, 0, stream>>>(h1b, perm, off, W2, b2, W3, t3b, n);
        // layer 3: out = agg(t3b) + b3   (fp32 output)
        gather16_kernel<<<g16, 256, 0, stream>>>(t3b, perm, off, b3, out, n);
    } else {
        const int BLK = 256;
        const int node_grid = (n + BLK - 1) / BLK;
        float* agg = (float*)d_ws;
        float* h   = agg + (size_t)n * 32;
        hipMemsetAsync(agg, 0, (size_t)n * 32 * sizeof(float), stream);
        scatter_kernel<32><<<((size_t)nE * 32 + BLK - 1) / BLK, BLK, 0, stream>>>(x, src, dst, agg, nE);
        dense_bias_kernel<32, 32, true><<<node_grid, BLK, 0, stream>>>(agg, W1, b1, h, n);
        hipMemsetAsync(agg, 0, (size_t)n * 32 * sizeof(float), stream);
        scatter_kernel<32><<<((size_t)nE * 32 + BLK - 1) / BLK, BLK, 0, stream>>>(h, src, dst, agg, nE);
        dense_bias_kernel<32, 32, true><<<node_grid, BLK, 0, stream>>>(agg, W2, b2, h, n);
        dense_kernel<32, 16><<<node_grid, BLK, 0, stream>>>(h, W3, agg, n);
        init_out_kernel<<<(n * 16 + BLK - 1) / BLK, BLK, 0, stream>>>(out, b3, n * 16);
        scatter_kernel<16><<<((size_t)nE * 16 + BLK - 1) / BLK, BLK, 0, stream>>>(agg, src, dst, out, nE);
    }
}